// Round 9
// baseline (728.289 us; speedup 1.0000x reference)
//
#include <hip/hip_runtime.h>
#include <cstdint>
#include <cstddef>

#define NN 20000
#define NE 320000
#define NG 256
#define NB 79   // ceil(NN/256)
#define MBK 157 // ceil(NN/128) — M-blocks per GEMM

typedef unsigned short u16;
typedef __attribute__((ext_vector_type(8))) short bf16x8;
typedef __attribute__((ext_vector_type(4))) float f32x4;

// ---------------- bf16 helpers (storage bf16, math fp32) ----------------
__device__ inline float b2f(u16 h){
  union { unsigned u; float f; } v; v.u = ((unsigned)h) << 16; return v.f;
}
__device__ inline u16 f2b(float f){
  union { float f; unsigned u; } v; v.f = f;
  unsigned r = v.u + 0x7FFFu + ((v.u >> 16) & 1u);   // round-nearest-even
  return (u16)(r >> 16);
}
__device__ inline void up8(const uint4& v, float* a){
  union { unsigned u; float f; } t;
  t.u = v.x << 16;         a[0] = t.f;
  t.u = v.x & 0xffff0000u; a[1] = t.f;
  t.u = v.y << 16;         a[2] = t.f;
  t.u = v.y & 0xffff0000u; a[3] = t.f;
  t.u = v.z << 16;         a[4] = t.f;
  t.u = v.z & 0xffff0000u; a[5] = t.f;
  t.u = v.w << 16;         a[6] = t.f;
  t.u = v.w & 0xffff0000u; a[7] = t.f;
}
__device__ inline unsigned pk2(float a, float b){
  return (unsigned)f2b(a) | (((unsigned)f2b(b)) << 16);
}

__device__ inline void gload_lds16(const void* g, void* l){
  __builtin_amdgcn_global_load_lds(
      (const __attribute__((address_space(1))) unsigned int*)g,
      (__attribute__((address_space(3))) unsigned int*)l, 16, 0, 0);
}

// ---------------- utility kernels ----------------

__global__ void k_zero(int* __restrict__ p, int n){
  int i = blockIdx.x*blockDim.x + threadIdx.x;
  if (i < n) p[i] = 0;
}

__global__ void k_deg(const int* __restrict__ ei, int* __restrict__ deg){
  int e = blockIdx.x*blockDim.x + threadIdx.x;
  if (e < NE) atomicAdd(&deg[ei[NE + e]], 1);   // dst = ei[1][e]
}

// two-level scan: counts[NN] -> offs[NN+1]; also emits dinv
__global__ void k_scan1(const int* __restrict__ counts, int* __restrict__ bsum,
                        float* __restrict__ dinv){
  __shared__ int sm[256];
  int b = blockIdx.x, tid = threadIdx.x, idx = b*256 + tid;
  int v = (idx < NN) ? counts[idx] : 0;
  if (idx < NN) dinv[idx] = rsqrtf(1.0f + (float)v);
  sm[tid] = v;
  __syncthreads();
  for (int d = 128; d > 0; d >>= 1){
    if (tid < d) sm[tid] += sm[tid + d];
    __syncthreads();
  }
  if (tid == 0) bsum[b] = sm[0];
}
__global__ void k_scan2(int* __restrict__ bsum){
  if (threadIdx.x == 0){
    int c = 0;
    for (int i = 0; i < NB; i++){ int t = bsum[i]; bsum[i] = c; c += t; }
    bsum[NB] = c;
  }
}
__global__ void k_scan3(const int* __restrict__ counts, const int* __restrict__ bsum,
                        int* __restrict__ offs){
  __shared__ int sm[256];
  int b = blockIdx.x, tid = threadIdx.x, idx = b*256 + tid;
  int v = (idx < NN) ? counts[idx] : 0;
  sm[tid] = v;
  __syncthreads();
  for (int d = 1; d < 256; d <<= 1){
    int t = (tid >= d) ? sm[tid - d] : 0;
    __syncthreads();
    sm[tid] += t;
    __syncthreads();
  }
  if (idx < NN) offs[idx] = bsum[b] + sm[tid] - v;
  if (idx == NN - 1) offs[NN] = bsum[NB];
}

__global__ void k_fill(const int* __restrict__ ei, const int* __restrict__ offs,
                       int* __restrict__ cur, int* __restrict__ srcs){
  int e = blockIdx.x*blockDim.x + threadIdx.x;
  if (e < NE){
    int s = ei[e];
    int d = ei[NE + e];
    int p = atomicAdd(&cur[d], 1);
    srcs[offs[d] + p] = s;
  }
}

__global__ void k_bounds(const int* __restrict__ batch, int* __restrict__ start){
  int i = blockIdx.x*blockDim.x + threadIdx.x;
  if (i < NN){
    int b  = batch[i];
    int bp = (i == 0) ? -1 : batch[i-1];
    for (int g = bp + 1; g <= b; g++) start[g] = i;
    if (i == NN - 1){
      for (int g = b + 1; g <= NG; g++) start[g] = NN;
    }
  }
}

// cast x (fp32 [NN,128]) to bf16 pre-scaled by dinv[row], XCD-blocked [8][NN][2] uint4
__global__ void k_cast(const float* __restrict__ x, uint4* __restrict__ xb,
                       const float* __restrict__ dinv, int total16){
  int t = blockIdx.x*blockDim.x + threadIdx.x;
  if (t >= total16) return;
  int i = t >> 4;          // row
  int c = t & 15;          // 16B chunk within row
  float di = dinv[i];
  const float* xp = x + (size_t)i*128 + c*8;
  float4 a = *(const float4*)xp;
  float4 b = *(const float4*)(xp + 4);
  uint4 o;
  o.x = pk2(a.x*di, a.y*di); o.y = pk2(a.z*di, a.w*di);
  o.z = pk2(b.x*di, b.y*di); o.w = pk2(b.z*di, b.w*di);
  int g = c >> 1, cl = c & 1;             // C8G = 2
  xb[(size_t)g*NN*2 + (size_t)i*2 + cl] = o;
}

// merged weight prep: 7 weights, fp32 [K,N] -> bf16 [N,K]
struct WPArgs {
  const float* w[7];
  u16* wt[7];
  int K[7], N[7];
  int tstart[8];   // tile prefix
};
__global__ __launch_bounds__(256) void k_wprep7(WPArgs a){
  __shared__ float sm[64][65];
  int bid = blockIdx.x;
  int wi = 0;
  while (wi < 6 && bid >= a.tstart[wi+1]) wi++;
  int tt = bid - a.tstart[wi];
  int K = a.K[wi], N = a.N[wi];
  int nk = K >> 6;
  int kb = (tt % nk) * 64, nb = (tt / nk) * 64;
  const float* w = a.w[wi];
  u16* wt = a.wt[wi];
  int tid = threadIdx.x;
  #pragma unroll
  for (int i = 0; i < 16; i++){
    int t = i*256 + tid;
    int r = t >> 6, c = t & 63;
    sm[r][c] = w[(size_t)(kb + r) * N + nb + c];
  }
  __syncthreads();
  #pragma unroll
  for (int i = 0; i < 16; i++){
    int t = i*256 + tid;
    int r = t >> 6, c = t & 63;
    wt[(size_t)(nb + r) * K + kb + c] = f2b(sm[c][r]);
  }
}

// ---------------- BN coefficient reduce: pstat partials -> per-channel sc/sh ----------------
// pstat layout: [mb][wm][2][Nc] plain stores from k_mfma STATS (no atomics — R8 lesson:
// 157-way contended far-atomics on 2K addresses). One rsqrt per CHANNEL here instead of
// per element in every consumer.
__global__ __launch_bounds__(256) void k_bncoef(const float* __restrict__ pst,
                        const float* __restrict__ gam, const float* __restrict__ bet,
                        float* __restrict__ scsh, int Nc){
  int c = blockIdx.x*blockDim.x + threadIdx.x;
  if (c >= Nc) return;
  float S = 0.f, S2 = 0.f;
  for (int m = 0; m < MBK*2; m++){
    S  += pst[((size_t)m*2 + 0)*Nc + c];
    S2 += pst[((size_t)m*2 + 1)*Nc + c];
  }
  float mean = S * (1.0f / NN);
  float var  = S2 * (1.0f / NN) - mean*mean;
  float rs = rsqrtf(var + 1e-5f);
  float sc = gam[c] * rs;
  scsh[c] = sc;
  scsh[Nc + c] = bet[c] - mean * sc;
}

// ---------------- BN+relu+dinv apply: raw row-major -> XCD-blocked [8][NN][C8G] ----------------
template<int C8>
__global__ __launch_bounds__(256) void k_bnscale(const uint4* __restrict__ src,
                        uint4* __restrict__ dst,
                        const float* __restrict__ dinv,
                        const float* __restrict__ scsh){
  constexpr int C8G = C8 / 8;
  constexpr int C = C8 * 8;
  int t = blockIdx.x*blockDim.x + threadIdx.x;
  if (t >= NN * C8) return;
  int i = t / C8;
  int c = t - i * C8;
  float sc[8], sh[8];
  #pragma unroll
  for (int k = 0; k < 8; k++){
    int ch = c*8 + k;
    sc[k] = scsh[ch];
    sh[k] = scsh[C + ch];
  }
  float di = dinv[i];
  float a[8];
  up8(src[t], a);
  #pragma unroll
  for (int k = 0; k < 8; k++) a[k] = fmaxf(fmaf(a[k], sc[k], sh[k]), 0.f) * di;
  uint4 o;
  o.x = pk2(a[0], a[1]); o.y = pk2(a[2], a[3]);
  o.z = pk2(a[4], a[5]); o.w = pk2(a[6], a[7]);
  int g = c / C8G, cl = c - g * C8G;
  dst[(size_t)g*NN*C8G + (size_t)i*C8G + cl] = o;
}

// ---------------- aggregation (bf16 in/out, fp32 accumulate) ----------------
// Input is XCD-BLOCKED [8][NN][C8G]: group g's slice is a contiguous, line-aligned
// region of NN*C8G*16 B (0.64..3.84 MB) -> L2-resident per XCD (bid%8 -> XCD).
// Inputs pre-scaled by dinv[row]; out row-major for the following GEMM.
template<int C8, int C8G>
__global__ __launch_bounds__(256) void k_agg_b(const uint4* __restrict__ in, uint4* __restrict__ out,
                        const float* __restrict__ dinv, const int* __restrict__ offs,
                        const int* __restrict__ srcs){
  int bid = blockIdx.x;
  int g = bid & 7;
  int t = (bid >> 3)*256 + threadIdx.x;
  if (t >= NN * C8G) return;
  int i = t / C8G;
  int cl = t - i * C8G;
  const uint4* base = in + (size_t)g*NN*C8G + cl;
  float acc[8];
  up8(base[(size_t)i * C8G], acc);       // self term (pre-scaled)
  int e = offs[i], e1 = offs[i + 1];
  for (; e + 4 <= e1; e += 4){
    int sA = srcs[e], sB = srcs[e+1], sC = srcs[e+2], sD = srcs[e+3];
    uint4 yA = base[(size_t)sA * C8G];
    uint4 yB = base[(size_t)sB * C8G];
    uint4 yC = base[(size_t)sC * C8G];
    uint4 yD = base[(size_t)sD * C8G];
    float b[8];
    up8(yA, b);
    #pragma unroll
    for (int k = 0; k < 8; k++) acc[k] += b[k];
    up8(yB, b);
    #pragma unroll
    for (int k = 0; k < 8; k++) acc[k] += b[k];
    up8(yC, b);
    #pragma unroll
    for (int k = 0; k < 8; k++) acc[k] += b[k];
    up8(yD, b);
    #pragma unroll
    for (int k = 0; k < 8; k++) acc[k] += b[k];
  }
  for (; e < e1; e++){
    int s = srcs[e];
    float b[8];
    up8(base[(size_t)s * C8G], b);
    #pragma unroll
    for (int k = 0; k < 8; k++) acc[k] += b[k];
  }
  float di = dinv[i];
  #pragma unroll
  for (int k = 0; k < 8; k++) acc[k] *= di;
  uint4 o;
  o.x = pk2(acc[0], acc[1]); o.y = pk2(acc[2], acc[3]);
  o.z = pk2(acc[4], acc[5]); o.w = pk2(acc[6], acc[7]);
  out[(size_t)i * C8 + g * C8G + cl] = o;
}

// ---------------- MFMA GEMM: A bf16 [M,K], BT bf16 [N,K] ----------------
// Work order: N fastest + in-kernel XCD-chunked bijective swizzle (A-panel L2 reuse).
// MODE: 0=bias, 1=bias+relu, 3=bias + relu(sc*C_old+sh) add (sc/sh precomputed by k_bncoef)
// STATS: per-column sum/sumsq of (acc+bias) -> plain stores to pst[mb][wm][2][Nc] (no atomics)
// SCALE: multiply final stored value by dinv[row]
// BLK: store output XCD-blocked [8][NN][Nc/64] uint4 (gather-input layout) to Co;
//      otherwise row-major to Co. MODE==3 reads old C row-major from C (C != Co when BLK).
template<int MODE, bool STATS, bool SCALE, bool BLK>
__global__ __launch_bounds__(256, 4) void k_mfma(const u16* __restrict__ A,
                                                 const u16* __restrict__ BT,
                                                 const float* __restrict__ bias,
                                                 const u16* __restrict__ C,
                                                 u16* __restrict__ Co,
                                                 float* __restrict__ pst,
                                                 const float* __restrict__ scsh,
                                                 const float* __restrict__ dv,
                                                 int M, int K, int Nc){
  __shared__ u16 S[128*128];          // staging: As = S[0:8192), Bs = S[8192:16384)
  u16* As = S;
  u16* Bs = S + 128*64;
  const int tid = threadIdx.x;
  const int lane = tid & 63;
  const int quad = lane >> 4;
  const int l16 = lane & 15;
  const int wid = tid >> 6;
  const int wm = wid & 1, wn = wid >> 1;

  // XCD-chunked bijective swizzle over the (Nt, Mt) work grid
  const int nwg = gridDim.x * gridDim.y;
  const int p = blockIdx.y * gridDim.x + blockIdx.x;
  const int xcd = p & 7;
  const int q = nwg >> 3, r = nwg & 7;
  const int w = (xcd < r ? xcd * (q + 1) : r * (q + 1) + (xcd - r) * q) + (p >> 3);
  const int bn = (w % gridDim.x) * 128;
  const int bm = (w / gridDim.x) * 128;

  f32x4 acc[4][4];
  #pragma unroll
  for (int i = 0; i < 4; i++)
    #pragma unroll
    for (int j = 0; j < 4; j++)
      acc[i][j] = (f32x4){0.f, 0.f, 0.f, 0.f};

  const int srow = tid >> 3;
  const int scol8 = tid & 7;
  for (int k0 = 0; k0 < K; k0 += 64){
    #pragma unroll
    for (int i = 0; i < 4; i++){
      int row = i*32 + srow;
      int gc = (scol8 ^ (row & 7)) * 8;
      int lofs = row*64 + scol8*8;
      gload_lds16(A + (size_t)(bm + row) * K + k0 + gc, As + lofs);
      gload_lds16(BT + (size_t)(bn + row) * K + k0 + gc, Bs + lofs);
    }
    __syncthreads();
    #pragma unroll
    for (int kk = 0; kk < 2; kk++){
      const int col8 = kk*4 + quad;
      bf16x8 af[4], bfr[4];
      #pragma unroll
      for (int mi = 0; mi < 4; mi++){
        int row = wm*64 + mi*16 + l16;
        af[mi] = *(const bf16x8*)(As + row*64 + ((col8 ^ (row & 7)) * 8));
      }
      #pragma unroll
      for (int ni = 0; ni < 4; ni++){
        int row = wn*64 + ni*16 + l16;
        bfr[ni] = *(const bf16x8*)(Bs + row*64 + ((col8 ^ (row & 7)) * 8));
      }
      #pragma unroll
      for (int mi = 0; mi < 4; mi++)
        #pragma unroll
        for (int ni = 0; ni < 4; ni++)
          acc[mi][ni] = __builtin_amdgcn_mfma_f32_16x16x32_bf16(af[mi], bfr[ni], acc[mi][ni], 0, 0, 0);
    }
    __syncthreads();
  }
  // register epilogue: bias (+stats, +relu), round to bf16 into LDS [row][col]
  #pragma unroll
  for (int ni = 0; ni < 4; ni++){
    int colL = wn*64 + ni*16 + l16;
    float bb = bias[bn + colL];
    float s = 0.f, s2 = 0.f;
    #pragma unroll
    for (int mi = 0; mi < 4; mi++){
      int rbase = wm*64 + mi*16 + quad*4;
      #pragma unroll
      for (int r2 = 0; r2 < 4; r2++){
        int rowL = rbase + r2;
        float v = acc[mi][ni][r2] + bb;
        if (STATS && (bm + rowL) < M){ s += v; s2 += v * v; }
        if (MODE == 1) v = fmaxf(v, 0.f);
        S[rowL*128 + colL] = f2b(v);
      }
    }
    if (STATS){
      s  += __shfl_xor(s, 16, 64);  s  += __shfl_xor(s, 32, 64);
      s2 += __shfl_xor(s2, 16, 64); s2 += __shfl_xor(s2, 32, 64);
      if (quad == 0){
        int mb = bm >> 7;
        size_t bi = ((size_t)(mb*2 + wm)*2)*Nc + bn + colL;
        pst[bi] = s;
        pst[bi + Nc] = s2;
      }
    }
  }
  __syncthreads();
  // blast: 16B per lane, full-line coalesced stores
  #pragma unroll
  for (int it = 0; it < 8; it++){
    int idx = it*256 + tid;
    int rl = idx >> 4, cq = idx & 15;
    int row = bm + rl;
    if (row < M){
      int col0 = bn + cq*8;
      uint4 wv = *(const uint4*)(S + rl*128 + cq*8);
      uint4 ou;
      if (MODE == 3){
        float di = SCALE ? dv[row] : 1.f;
        float o[8], ov[8];
        up8(wv, o);
        uint4 old = *(const uint4*)(C + (size_t)row * Nc + col0);
        up8(old, ov);
        #pragma unroll
        for (int k = 0; k < 8; k++){
          int ch = col0 + k;
          float sc = scsh[ch];
          float sh = scsh[Nc + ch];
          o[k] += fmaxf(fmaf(ov[k], sc, sh), 0.f);
          if (SCALE) o[k] *= di;
        }
        ou.x = pk2(o[0], o[1]); ou.y = pk2(o[2], o[3]);
        ou.z = pk2(o[4], o[5]); ou.w = pk2(o[6], o[7]);
      } else if (SCALE){
        float di = dv[row];
        float o[8];
        up8(wv, o);
        #pragma unroll
        for (int k = 0; k < 8; k++) o[k] *= di;
        ou.x = pk2(o[0], o[1]); ou.y = pk2(o[2], o[3]);
        ou.z = pk2(o[4], o[5]); ou.w = pk2(o[6], o[7]);
      } else {
        ou = wv;
      }
      if (BLK){
        int chpg = Nc >> 3;                 // channels per XCD group
        int g = col0 / chpg;
        int c8g = chpg >> 3;                // uint4 per row slice
        int cl = (col0 - g * chpg) >> 3;
        *((uint4*)Co + (size_t)g*NN*c8g + (size_t)row*c8g + cl) = ou;
      } else {
        *(uint4*)(Co + (size_t)row * Nc + col0) = ou;
      }
    }
  }
}

// ---------------- fp32 split-K GEMM (MLP tail, M=256) ----------------
// Each block writes its K-chunk partial to Cp[z][M][Nc] with plain stores;
// k_redsk sums the SPLITS partials + bias.
template<bool RELUA>
__global__ __launch_bounds__(256) void k_gemm_sk(const float* __restrict__ A,
                                                 const float* __restrict__ B,
                                                 float* __restrict__ Cp,
                                                 int M, int K, int Nc){
  __shared__ float As[16][68];
  __shared__ float Bs[16][64];
  const int tid = threadIdx.x;
  const int tx = tid & 15, ty = tid >> 4;
  const int bm = blockIdx.x * 64, bn = blockIdx.y * 64;
  const int kchunk = K / gridDim.z;
  const int ks = blockIdx.z * kchunk, ke = ks + kchunk;
  const int arow = tid >> 2, akq = (tid & 3) << 2;
  const int brow = tid >> 4, bcol = (tid & 15) << 2;
  float acc[4][4] = {{0.f}};
  const bool aval = (bm + arow) < M;
  const float* Aptr = A + (size_t)(bm + arow) * K + akq;
  const float* Bptr = B + (size_t)brow * Nc + bn + bcol;
  for (int k0 = ks; k0 < ke; k0 += 16){
    float4 av = make_float4(0.f, 0.f, 0.f, 0.f);
    if (aval) av = *(const float4*)(Aptr + k0);
    if (RELUA){
      av.x = fmaxf(av.x, 0.f); av.y = fmaxf(av.y, 0.f);
      av.z = fmaxf(av.z, 0.f); av.w = fmaxf(av.w, 0.f);
    }
    float4 bv = *(const float4*)(Bptr + (size_t)k0 * Nc);
    As[akq + 0][arow] = av.x;
    As[akq + 1][arow] = av.y;
    As[akq + 2][arow] = av.z;
    As[akq + 3][arow] = av.w;
    *(float4*)&Bs[brow][bcol] = bv;
    __syncthreads();
    #pragma unroll
    for (int kk = 0; kk < 16; kk++){
      const float4 a = *(const float4*)(&As[kk][ty << 2]);
      const float4 b = *(const float4*)(&Bs[kk][tx << 2]);
      const float ar[4] = {a.x, a.y, a.z, a.w};
      const float br[4] = {b.x, b.y, b.z, b.w};
      #pragma unroll
      for (int i = 0; i < 4; i++)
        #pragma unroll
        for (int j = 0; j < 4; j++)
          acc[i][j] = fmaf(ar[i], br[j], acc[i][j]);
    }
    __syncthreads();
  }
  const int col = bn + (tx << 2);
  float* base = Cp + (size_t)blockIdx.z * M * Nc;
  #pragma unroll
  for (int i = 0; i < 4; i++){
    int row = bm + (ty << 2) + i;
    if (row < M){
      *(float4*)(base + (size_t)row * Nc + col) =
          make_float4(acc[i][0], acc[i][1], acc[i][2], acc[i][3]);
    }
  }
}

// reduce SPLITS partials + bias -> out (fp32, float4-vectorized)
template<int SPLITS>
__global__ __launch_bounds__(256) void k_redsk(const float4* __restrict__ part,
                                               const float* __restrict__ bias,
                                               float4* __restrict__ out,
                                               int M, int Nc4){
  int t = blockIdx.x*blockDim.x + threadIdx.x;
  int total = M * Nc4;
  if (t >= total) return;
  int col4 = t % Nc4;
  float4 s = ((const float4*)bias)[col4];
  #pragma unroll
  for (int z = 0; z < SPLITS; z++){
    float4 v = part[(size_t)z * total + t];
    s.x += v.x; s.y += v.y; s.z += v.z; s.w += v.w;
  }
  out[t] = s;
}

// ---------------- mean pool: h2 bf16 [NN,1024] -> pooled fp32 [NG,1024] ----------------
__global__ __launch_bounds__(256) void k_pool_b(const u16* __restrict__ h,
                                                const int* __restrict__ start,
                                                float* __restrict__ pooled){
  __shared__ float sm[128*8];
  int g = blockIdx.x;
  int half = threadIdx.x >> 7;
  int cb = threadIdx.x & 127;
  int c = cb << 3;
  int r0 = start[g], r1 = start[g + 1];
  float acc[8] = {0.f,0.f,0.f,0.f,0.f,0.f,0.f,0.f};
  for (int r = r0 + half; r < r1; r += 2){
    float b[8];
    up8(*(const uint4*)(h + (size_t)r * 1024 + c), b);
    #pragma unroll
    for (int k = 0; k < 8; k++) acc[k] += b[k];
  }
  if (half){
    #pragma unroll
    for (int k = 0; k < 8; k++) sm[cb*8 + k] = acc[k];
  }
  __syncthreads();
  if (!half){
    float inv = (r1 > r0) ? (1.0f / (float)(r1 - r0)) : 0.0f;
    float o[8];
    #pragma unroll
    for (int k = 0; k < 8; k++) o[k] = (acc[k] + sm[cb*8 + k]) * inv;
    float4* dst = (float4*)(pooled + (size_t)g * 1024 + c);
    dst[0] = make_float4(o[0], o[1], o[2], o[3]);
    dst[1] = make_float4(o[4], o[5], o[6], o[7]);
  }
}

// ---------------- host launcher ----------------

extern "C" void kernel_launch(void* const* d_in, const int* in_sizes, int n_in,
                              void* d_out, int out_size, void* d_ws, size_t ws_size,
                              hipStream_t stream) {
  const float* x    = (const float*)d_in[0];
  const int*   ei   = (const int*)d_in[1];
  const int*   bat  = (const int*)d_in[2];
  const float* w0   = (const float*)d_in[3];
  const float* b0   = (const float*)d_in[4];
  const float* a_w1 = (const float*)d_in[5],  *a_b1  = (const float*)d_in[6];
  const float* a_g1 = (const float*)d_in[7],  *a_be1 = (const float*)d_in[8];
  const float* a_w2 = (const float*)d_in[9],  *a_b2  = (const float*)d_in[10];
  const float* a_g2 = (const float*)d_in[11], *a_be2 = (const float*)d_in[12];
  const float* a_w3 = (const float*)d_in[13], *a_b3  = (const float*)d_in[14];
  const float* c_w1 = (const float*)d_in[15], *c_b1  = (const float*)d_in[16];
  const float* c_g1 = (const float*)d_in[17], *c_be1 = (const float*)d_in[18];
  const float* c_w2 = (const float*)d_in[19], *c_b2  = (const float*)d_in[20];
  const float* c_g2 = (const float*)d_in[21], *c_be2 = (const float*)d_in[22];
  const float* c_w3 = (const float*)d_in[23], *c_b3  = (const float*)d_in[24];
  const float* mw1  = (const float*)d_in[25], *mb1   = (const float*)d_in[26];
  const float* mw2  = (const float*)d_in[27], *mb2   = (const float*)d_in[28];
  float* out = (float*)d_out;

  char* pp = (char*)d_ws;
  auto alloc = [&](size_t b)->char*{ char* r = pp; pp += (b + 255) & ~(size_t)255; return r; };

  const size_t CH = (size_t)NN * 2;
  char* R = alloc(2304 * CH);                      // 92.16 MB
  float* dinv = (float*)alloc((size_t)NN * 4);
  int* icomb  = (int*)alloc((size_t)2 * NN * 4);   // deg + cur
  int* deg    = icomb;
  int* cur    = icomb + NN;
  int* offs   = (int*)alloc((size_t)(NN + 1) * 4);
  int* bsum   = (int*)alloc((size_t)(NB + 1) * 4);
  int* srcs   = (int*)alloc((size_t)NE * 4);
  int* startg = (int*)alloc((size_t)(NG + 1) * 4);
  float* SB   = (float*)alloc(5376 * 4);           // sc||sh per BN layer
  float* sA1 = SB;          // 2*384
  float* sA2 = SB + 768;    // 2*512
  float* sC1 = SB + 1792;   // 2*768
  float* sC2 = SB + 3328;   // 2*1024
  float* pstat = (float*)alloc((size_t)MBK * 2 * 2 * 1024 * 4);  // 2.57 MB stats scratch
  u16* WT  = (u16*)alloc(2162688 * 2);             // 4.33 MB
  u16* wt0  = WT;                // 256x128
  u16* wtA1 = WT + 32768;        // 384x256
  u16* wtA2 = WT + 131072;       // 512x384
  u16* wtA3 = WT + 327680;       // 512x256
  u16* wtC1 = WT + 458752;       // 768x512
  u16* wtC2 = WT + 851968;       // 1024x768
  u16* wtC3 = WT + 1638400;      // 1024x512
  float* P  = (float*)WT;        // overlaid with WT (disjoint lifetime)
  float* Hh = P + (size_t)NG * 1024;

  // slot map (lifetime-checked; blocked buffers marked [B]):
  //  xb[B]   0-127    k_cast -> agg(ax)
  //  ax      128-255  -> stem GEMM
  //  h0[B]   256-511  stem GEMM -> agg(ah0)
  //  ah0     512-767  -> GEMM wtA1, wtA3
  //  t1raw   768-1151 GEMM wtA1 -> bnscale
  //  t1b[B]  1152-1535 bnscale -> agg(at)
  //  at      1536-1919 -> GEMM wtA2
  //  h1raw   0-511    GEMM wtA2 -> mode3 old-read
  //  h1b[B]  768-1279 mode3 GEMM -> agg(ah1)
  //  ah1     1792-2303 -> GEMM wtC1, wtC3
  //  u1raw   0-767    GEMM wtC1 -> bnscale
  //  u1b[B]  768-1535 bnscale -> agg(au)
  //  au      0-767    -> GEMM wtC2
  //  h2      768-1791 GEMM wtC2 -> wtC3 (in-place RMW) -> pool
  //  part1   0-255    gemm_sk1 partials -> redsk1   [dead: au]
  //  part2   256-511  gemm_sk2 partials -> redsk2
  auto slot = [&](int s)->u16*{ return (u16*)(R + (size_t)s * CH); };
  u16* xb    = slot(0);
  u16* ax    = slot(128);
  u16* h0    = slot(256);
  u16* ah0   = slot(512);
  u16* t1raw = slot(768);
  u16* t1b   = slot(1152);
  u16* at    = slot(1536);
  u16* h1raw = slot(0);
  u16* h1b   = slot(768);
  u16* ah1   = slot(1792);
  u16* u1raw = slot(0);
  u16* u1b   = slot(768);
  u16* au    = slot(0);
  u16* h2    = slot(768);
  float* part1 = (float*)slot(0);
  float* part2 = (float*)slot(256);

  auto cdiv = [](int a, int b){ return (a + b - 1) / b; };

  // graph preprocessing
  k_zero<<<cdiv(2*NN,256),256,0,stream>>>(icomb, 2*NN);
  k_deg <<<cdiv(NE,256),256,0,stream>>>(ei, deg);
  k_scan1<<<NB,256,0,stream>>>(deg, bsum, dinv);
  k_scan2<<<1,64,0,stream>>>(bsum);
  k_scan3<<<NB,256,0,stream>>>(deg, bsum, offs);
  k_fill<<<cdiv(NE,256),256,0,stream>>>(ei, offs, cur, srcs);
  k_bounds<<<cdiv(NN,256),256,0,stream>>>(bat, startg);
  k_cast<<<cdiv(NN*16,256),256,0,stream>>>(x, (uint4*)xb, dinv, NN*16);

  // merged weight prep (fp32 [K,N] -> bf16 [N,K], 7 weights, 1 launch)
  {
    WPArgs wa;
    const float* ws[7] = {w0, a_w1, a_w2, a_w3, c_w1, c_w2, c_w3};
    u16* wts[7] = {wt0, wtA1, wtA2, wtA3, wtC1, wtC2, wtC3};
    int Ks[7] = {128, 256, 384, 256, 512, 768, 512};
    int Ns[7] = {256, 384, 512, 512, 768, 1024, 1024};
    int acc = 0;
    for (int i = 0; i < 7; i++){
      wa.w[i] = ws[i]; wa.wt[i] = wts[i]; wa.K[i] = Ks[i]; wa.N[i] = Ns[i];
      wa.tstart[i] = acc;
      acc += (Ks[i]/64) * (Ns[i]/64);
    }
    wa.tstart[7] = acc;
    k_wprep7<<<acc,256,0,stream>>>(wa);
  }

  // agg: blocked-gather, 8 XCD groups always
  auto agg = [&](const u16* in, u16* o, int C){
    int C8 = C / 8;
    int C8G = C8 / 8;
    int gb = 8 * cdiv(NN * C8G, 256);
    switch (C8){
      case 16: k_agg_b<16, 2><<<gb,256,0,stream>>>((const uint4*)in,(uint4*)o,dinv,offs,srcs); break;
      case 32: k_agg_b<32, 4><<<gb,256,0,stream>>>((const uint4*)in,(uint4*)o,dinv,offs,srcs); break;
      case 48: k_agg_b<48, 6><<<gb,256,0,stream>>>((const uint4*)in,(uint4*)o,dinv,offs,srcs); break;
      case 64: k_agg_b<64, 8><<<gb,256,0,stream>>>((const uint4*)in,(uint4*)o,dinv,offs,srcs); break;
      case 96: k_agg_b<96,12><<<gb,256,0,stream>>>((const uint4*)in,(uint4*)o,dinv,offs,srcs); break;
      default: break;
    }
  };
  // GEMM modes: 0 = raw+stats-partials (row-major); 1b = relu*dinv, BLOCKED out;
  // 3b = (relu(sc*old+sh)+acc)*dinv, BLOCKED out; 3 = relu(sc*old+sh)+acc, row-major in-place
  auto gemm0 = [&](const u16* A, const u16* BT_, const float* bi, u16* Cc,
                   int K, int Nc){
    dim3 g(Nc/128, cdiv(NN,128));
    k_mfma<0,true,false,false><<<g,256,0,stream>>>(A, BT_, bi, Cc, Cc, pstat, nullptr, dinv, NN, K, Nc);
  };
  auto bncoef = [&](const float* gm, const float* bt, float* scsh, int Nc){
    k_bncoef<<<cdiv(Nc,256),256,0,stream>>>(pstat, gm, bt, scsh, Nc);
  };
  auto gemm1b = [&](const u16* A, const u16* BT_, const float* bi, u16* Cob,
                    int K, int Nc){
    dim3 g(Nc/128, cdiv(NN,128));
    k_mfma<1,false,true,true><<<g,256,0,stream>>>(A, BT_, bi, Cob, Cob, nullptr, nullptr, dinv, NN, K, Nc);
  };
  auto gemm3b = [&](const u16* A, const u16* BT_, const float* bi, const u16* Cold, u16* Cob,
                    int K, int Nc, const float* scsh){
    dim3 g(Nc/128, cdiv(NN,128));
    k_mfma<3,false,true,true><<<g,256,0,stream>>>(A, BT_, bi, Cold, Cob, nullptr, scsh, dinv, NN, K, Nc);
  };
  auto gemm3 = [&](const u16* A, const u16* BT_, const float* bi, u16* Cc,
                   int K, int Nc, const float* scsh){
    dim3 g(Nc/128, cdiv(NN,128));
    k_mfma<3,false,false,false><<<g,256,0,stream>>>(A, BT_, bi, Cc, Cc, nullptr, scsh, dinv, NN, K, Nc);
  };

  // stem
  agg(xb, ax, 128);
  gemm1b(ax, wt0, b0, h0, 128, 256);                       // h0[B] = relu(ax@w0+b0)*dinv
  // block0 (256 -> 384 -> 512)
  agg(h0, ah0, 256);
  gemm0(ah0, wtA1, a_b1, t1raw, 256, 384);                 // t1raw + stats partials
  bncoef(a_g1, a_be1, sA1, 384);
  k_bnscale<48><<<cdiv(NN*48,256),256,0,stream>>>((const uint4*)t1raw, (uint4*)t1b, dinv, sA1);
  agg(t1b, at, 384);                                       // at = agg(T(t1raw))
  gemm0(at, wtA2, a_b2, h1raw, 384, 512);                  // t2raw + stats partials
  bncoef(a_g2, a_be2, sA2, 512);
  gemm3b(ah0, wtA3, a_b3, h1raw, h1b, 256, 512, sA2);      // h1b[B]
  // block1 (512 -> 768 -> 1024)
  agg(h1b, ah1, 512);
  gemm0(ah1, wtC1, c_b1, u1raw, 512, 768);                 // u1raw + stats partials
  bncoef(c_g1, c_be1, sC1, 768);
  k_bnscale<96><<<cdiv(NN*96,256),256,0,stream>>>((const uint4*)u1raw, (uint4*)u1b, dinv, sC1);
  agg(u1b, au, 768);                                       // au = agg(T(u1raw))
  gemm0(au, wtC2, c_b2, h2, 768, 1024);                    // u2raw + stats partials
  bncoef(c_g2, c_be2, sC2, 1024);
  gemm3(ah1, wtC3, c_b3, h2, 512, 1024, sC2);              // h2 final (row-major)
  // pool + MLP (fp32 split-K, partials + reduce — no global atomics)
  k_pool_b<<<NG,256,0,stream>>>(h2, startg, P);
  {
    dim3 g1(cdiv(NG,64), 1024/64, 8);
    k_gemm_sk<false><<<g1,256,0,stream>>>(P, mw1, part1, NG, 1024, 1024);
    k_redsk<8><<<cdiv(NG*256,256),256,0,stream>>>((const float4*)part1, mb1, (float4*)Hh, NG, 256);
    dim3 g2(cdiv(NG,64), 768/64, 8);
    k_gemm_sk<true><<<g2,256,0,stream>>>(Hh, mw2, part2, NG, 1024, 768);
    k_redsk<8><<<cdiv(NG*192,256),256,0,stream>>>((const float4*)part2, mb2, (float4*)out, NG, 192);
  }
}

// Round 10
// 574.136 us; speedup vs baseline: 1.2685x; 1.2685x over previous
//
#include <hip/hip_runtime.h>
#include <cstdint>
#include <cstddef>

#define NN 20000
#define NE 320000
#define NG 256
#define NB 79   // ceil(NN/256)
#define MBK 157 // ceil(NN/128) — M-blocks per GEMM

typedef unsigned short u16;
typedef __attribute__((ext_vector_type(8))) short bf16x8;
typedef __attribute__((ext_vector_type(4))) float f32x4;

// ---------------- bf16 helpers (storage bf16, math fp32) ----------------
__device__ inline float b2f(u16 h){
  union { unsigned u; float f; } v; v.u = ((unsigned)h) << 16; return v.f;
}
__device__ inline u16 f2b(float f){
  union { float f; unsigned u; } v; v.f = f;
  unsigned r = v.u + 0x7FFFu + ((v.u >> 16) & 1u);   // round-nearest-even
  return (u16)(r >> 16);
}
__device__ inline void up8(const uint4& v, float* a){
  union { unsigned u; float f; } t;
  t.u = v.x << 16;         a[0] = t.f;
  t.u = v.x & 0xffff0000u; a[1] = t.f;
  t.u = v.y << 16;         a[2] = t.f;
  t.u = v.y & 0xffff0000u; a[3] = t.f;
  t.u = v.z << 16;         a[4] = t.f;
  t.u = v.z & 0xffff0000u; a[5] = t.f;
  t.u = v.w << 16;         a[6] = t.f;
  t.u = v.w & 0xffff0000u; a[7] = t.f;
}
__device__ inline unsigned pk2(float a, float b){
  return (unsigned)f2b(a) | (((unsigned)f2b(b)) << 16);
}

__device__ inline void gload_lds16(const void* g, void* l){
  __builtin_amdgcn_global_load_lds(
      (const __attribute__((address_space(1))) unsigned int*)g,
      (__attribute__((address_space(3))) unsigned int*)l, 16, 0, 0);
}

// ---------------- utility kernels ----------------

__global__ void k_zero(int* __restrict__ p, int n){
  int i = blockIdx.x*blockDim.x + threadIdx.x;
  if (i < n) p[i] = 0;
}

__global__ void k_deg(const int* __restrict__ ei, int* __restrict__ deg){
  int e = blockIdx.x*blockDim.x + threadIdx.x;
  if (e < NE) atomicAdd(&deg[ei[NE + e]], 1);   // dst = ei[1][e]
}

// two-level scan: counts[NN] -> offs[NN+1]; also emits dinv
__global__ void k_scan1(const int* __restrict__ counts, int* __restrict__ bsum,
                        float* __restrict__ dinv){
  __shared__ int sm[256];
  int b = blockIdx.x, tid = threadIdx.x, idx = b*256 + tid;
  int v = (idx < NN) ? counts[idx] : 0;
  if (idx < NN) dinv[idx] = rsqrtf(1.0f + (float)v);
  sm[tid] = v;
  __syncthreads();
  for (int d = 128; d > 0; d >>= 1){
    if (tid < d) sm[tid] += sm[tid + d];
    __syncthreads();
  }
  if (tid == 0) bsum[b] = sm[0];
}
__global__ void k_scan2(int* __restrict__ bsum){
  if (threadIdx.x == 0){
    int c = 0;
    for (int i = 0; i < NB; i++){ int t = bsum[i]; bsum[i] = c; c += t; }
    bsum[NB] = c;
  }
}
__global__ void k_scan3(const int* __restrict__ counts, const int* __restrict__ bsum,
                        int* __restrict__ offs){
  __shared__ int sm[256];
  int b = blockIdx.x, tid = threadIdx.x, idx = b*256 + tid;
  int v = (idx < NN) ? counts[idx] : 0;
  sm[tid] = v;
  __syncthreads();
  for (int d = 1; d < 256; d <<= 1){
    int t = (tid >= d) ? sm[tid - d] : 0;
    __syncthreads();
    sm[tid] += t;
    __syncthreads();
  }
  if (idx < NN) offs[idx] = bsum[b] + sm[tid] - v;
  if (idx == NN - 1) offs[NN] = bsum[NB];
}

__global__ void k_fill(const int* __restrict__ ei, const int* __restrict__ offs,
                       int* __restrict__ cur, int* __restrict__ srcs){
  int e = blockIdx.x*blockDim.x + threadIdx.x;
  if (e < NE){
    int s = ei[e];
    int d = ei[NE + e];
    int p = atomicAdd(&cur[d], 1);
    srcs[offs[d] + p] = s;
  }
}

__global__ void k_bounds(const int* __restrict__ batch, int* __restrict__ start){
  int i = blockIdx.x*blockDim.x + threadIdx.x;
  if (i < NN){
    int b  = batch[i];
    int bp = (i == 0) ? -1 : batch[i-1];
    for (int g = bp + 1; g <= b; g++) start[g] = i;
    if (i == NN - 1){
      for (int g = b + 1; g <= NG; g++) start[g] = NN;
    }
  }
}

// cast x (fp32 [NN,128]) to bf16 pre-scaled by dinv[row], XCD-blocked [8][NN][2] uint4
__global__ void k_cast(const float* __restrict__ x, uint4* __restrict__ xb,
                       const float* __restrict__ dinv, int total16){
  int t = blockIdx.x*blockDim.x + threadIdx.x;
  if (t >= total16) return;
  int i = t >> 4;          // row
  int c = t & 15;          // 16B chunk within row
  float di = dinv[i];
  const float* xp = x + (size_t)i*128 + c*8;
  float4 a = *(const float4*)xp;
  float4 b = *(const float4*)(xp + 4);
  uint4 o;
  o.x = pk2(a.x*di, a.y*di); o.y = pk2(a.z*di, a.w*di);
  o.z = pk2(b.x*di, b.y*di); o.w = pk2(b.z*di, b.w*di);
  int g = c >> 1, cl = c & 1;             // C8G = 2
  xb[(size_t)g*NN*2 + (size_t)i*2 + cl] = o;
}

// merged weight prep: 7 weights, fp32 [K,N] -> bf16 [N,K]
struct WPArgs {
  const float* w[7];
  u16* wt[7];
  int K[7], N[7];
  int tstart[8];   // tile prefix
};
__global__ __launch_bounds__(256) void k_wprep7(WPArgs a){
  __shared__ float sm[64][65];
  int bid = blockIdx.x;
  int wi = 0;
  while (wi < 6 && bid >= a.tstart[wi+1]) wi++;
  int tt = bid - a.tstart[wi];
  int K = a.K[wi], N = a.N[wi];
  int nk = K >> 6;
  int kb = (tt % nk) * 64, nb = (tt / nk) * 64;
  const float* w = a.w[wi];
  u16* wt = a.wt[wi];
  int tid = threadIdx.x;
  #pragma unroll
  for (int i = 0; i < 16; i++){
    int t = i*256 + tid;
    int r = t >> 6, c = t & 63;
    sm[r][c] = w[(size_t)(kb + r) * N + nb + c];
  }
  __syncthreads();
  #pragma unroll
  for (int i = 0; i < 16; i++){
    int t = i*256 + tid;
    int r = t >> 6, c = t & 63;
    wt[(size_t)(nb + r) * K + kb + c] = f2b(sm[c][r]);
  }
}

// ---------------- BN coefficient reduce: pstat partials -> per-channel sc/sh ----------------
// pstat layout: [m][2][Nc], m in [0, MBK*2). R9 lesson: Nc-thread serial reduction
// was 50us at 0.12% occupancy. Parallelize over m: block = 32 channels x 8 m-slices,
// each thread ~40 coalesced independent loads; LDS tree over slices.
__global__ __launch_bounds__(256) void k_bncoef(const float* __restrict__ pst,
                        const float* __restrict__ gam, const float* __restrict__ bet,
                        float* __restrict__ scsh, int Nc){
  __shared__ float red[2][8][32];
  int ci = threadIdx.x & 31;
  int ms = threadIdx.x >> 5;       // 0..7
  int c = blockIdx.x * 32 + ci;
  float S = 0.f, S2 = 0.f;
  for (int m = ms; m < MBK*2; m += 8){
    S  += pst[((size_t)m*2 + 0)*Nc + c];
    S2 += pst[((size_t)m*2 + 1)*Nc + c];
  }
  red[0][ms][ci] = S; red[1][ms][ci] = S2;
  __syncthreads();
  if (ms == 0){
    #pragma unroll
    for (int k = 1; k < 8; k++){ S += red[0][k][ci]; S2 += red[1][k][ci]; }
    float mean = S * (1.0f / NN);
    float var  = S2 * (1.0f / NN) - mean*mean;
    float rs = rsqrtf(var + 1e-5f);
    float sc = gam[c] * rs;
    scsh[c] = sc;
    scsh[Nc + c] = bet[c] - mean * sc;
  }
}

// ---------------- BN+relu+dinv apply: raw row-major -> XCD-blocked [8][NN][C8G] ----------------
template<int C8>
__global__ __launch_bounds__(256) void k_bnscale(const uint4* __restrict__ src,
                        uint4* __restrict__ dst,
                        const float* __restrict__ dinv,
                        const float* __restrict__ scsh){
  constexpr int C8G = C8 / 8;
  constexpr int C = C8 * 8;
  int t = blockIdx.x*blockDim.x + threadIdx.x;
  if (t >= NN * C8) return;
  int i = t / C8;
  int c = t - i * C8;
  float sc[8], sh[8];
  #pragma unroll
  for (int k = 0; k < 8; k++){
    int ch = c*8 + k;
    sc[k] = scsh[ch];
    sh[k] = scsh[C + ch];
  }
  float di = dinv[i];
  float a[8];
  up8(src[t], a);
  #pragma unroll
  for (int k = 0; k < 8; k++) a[k] = fmaxf(fmaf(a[k], sc[k], sh[k]), 0.f) * di;
  uint4 o;
  o.x = pk2(a[0], a[1]); o.y = pk2(a[2], a[3]);
  o.z = pk2(a[4], a[5]); o.w = pk2(a[6], a[7]);
  int g = c / C8G, cl = c - g * C8G;
  dst[(size_t)g*NN*C8G + (size_t)i*C8G + cl] = o;
}

// ---------------- aggregation (bf16 in/out, fp32 accumulate) ----------------
// Input is XCD-BLOCKED [8][NN][C8G]: group g's slice is a contiguous, line-aligned
// region of NN*C8G*16 B (0.64..3.84 MB) -> L2-resident per XCD (bid%8 -> XCD).
// Inputs pre-scaled by dinv[row]; out row-major for the following GEMM.
template<int C8, int C8G>
__global__ __launch_bounds__(256) void k_agg_b(const uint4* __restrict__ in, uint4* __restrict__ out,
                        const float* __restrict__ dinv, const int* __restrict__ offs,
                        const int* __restrict__ srcs){
  int bid = blockIdx.x;
  int g = bid & 7;
  int t = (bid >> 3)*256 + threadIdx.x;
  if (t >= NN * C8G) return;
  int i = t / C8G;
  int cl = t - i * C8G;
  const uint4* base = in + (size_t)g*NN*C8G + cl;
  float acc[8];
  up8(base[(size_t)i * C8G], acc);       // self term (pre-scaled)
  int e = offs[i], e1 = offs[i + 1];
  for (; e + 4 <= e1; e += 4){
    int sA = srcs[e], sB = srcs[e+1], sC = srcs[e+2], sD = srcs[e+3];
    uint4 yA = base[(size_t)sA * C8G];
    uint4 yB = base[(size_t)sB * C8G];
    uint4 yC = base[(size_t)sC * C8G];
    uint4 yD = base[(size_t)sD * C8G];
    float b[8];
    up8(yA, b);
    #pragma unroll
    for (int k = 0; k < 8; k++) acc[k] += b[k];
    up8(yB, b);
    #pragma unroll
    for (int k = 0; k < 8; k++) acc[k] += b[k];
    up8(yC, b);
    #pragma unroll
    for (int k = 0; k < 8; k++) acc[k] += b[k];
    up8(yD, b);
    #pragma unroll
    for (int k = 0; k < 8; k++) acc[k] += b[k];
  }
  for (; e < e1; e++){
    int s = srcs[e];
    float b[8];
    up8(base[(size_t)s * C8G], b);
    #pragma unroll
    for (int k = 0; k < 8; k++) acc[k] += b[k];
  }
  float di = dinv[i];
  #pragma unroll
  for (int k = 0; k < 8; k++) acc[k] *= di;
  uint4 o;
  o.x = pk2(acc[0], acc[1]); o.y = pk2(acc[2], acc[3]);
  o.z = pk2(acc[4], acc[5]); o.w = pk2(acc[6], acc[7]);
  out[(size_t)i * C8 + g * C8G + cl] = o;
}

// ---------------- MFMA GEMM: A bf16 [M,K], BT bf16 [N,K] ----------------
// Work order: N fastest + in-kernel XCD-chunked bijective swizzle (A-panel L2 reuse).
// MODE: 0=bias, 1=bias+relu, 3=bias + relu(sc*C_old+sh) add (sc/sh precomputed by k_bncoef)
// STATS: per-column sum/sumsq of (acc+bias) -> plain stores to pst[mb][wm][2][Nc] (no atomics)
// SCALE: multiply final stored value by dinv[row]
// BLK: store output XCD-blocked [8][NN][Nc/64] uint4 (gather-input layout) to Co;
//      otherwise row-major to Co. MODE==3 reads old C row-major from C (C != Co when BLK).
template<int MODE, bool STATS, bool SCALE, bool BLK>
__global__ __launch_bounds__(256, 4) void k_mfma(const u16* __restrict__ A,
                                                 const u16* __restrict__ BT,
                                                 const float* __restrict__ bias,
                                                 const u16* __restrict__ C,
                                                 u16* __restrict__ Co,
                                                 float* __restrict__ pst,
                                                 const float* __restrict__ scsh,
                                                 const float* __restrict__ dv,
                                                 int M, int K, int Nc){
  __shared__ u16 S[128*128];          // staging: As = S[0:8192), Bs = S[8192:16384)
  u16* As = S;
  u16* Bs = S + 128*64;
  const int tid = threadIdx.x;
  const int lane = tid & 63;
  const int quad = lane >> 4;
  const int l16 = lane & 15;
  const int wid = tid >> 6;
  const int wm = wid & 1, wn = wid >> 1;

  // XCD-chunked bijective swizzle over the (Nt, Mt) work grid
  const int nwg = gridDim.x * gridDim.y;
  const int p = blockIdx.y * gridDim.x + blockIdx.x;
  const int xcd = p & 7;
  const int q = nwg >> 3, r = nwg & 7;
  const int w = (xcd < r ? xcd * (q + 1) : r * (q + 1) + (xcd - r) * q) + (p >> 3);
  const int bn = (w % gridDim.x) * 128;
  const int bm = (w / gridDim.x) * 128;

  f32x4 acc[4][4];
  #pragma unroll
  for (int i = 0; i < 4; i++)
    #pragma unroll
    for (int j = 0; j < 4; j++)
      acc[i][j] = (f32x4){0.f, 0.f, 0.f, 0.f};

  const int srow = tid >> 3;
  const int scol8 = tid & 7;
  for (int k0 = 0; k0 < K; k0 += 64){
    #pragma unroll
    for (int i = 0; i < 4; i++){
      int row = i*32 + srow;
      int gc = (scol8 ^ (row & 7)) * 8;
      int lofs = row*64 + scol8*8;
      gload_lds16(A + (size_t)(bm + row) * K + k0 + gc, As + lofs);
      gload_lds16(BT + (size_t)(bn + row) * K + k0 + gc, Bs + lofs);
    }
    __syncthreads();
    #pragma unroll
    for (int kk = 0; kk < 2; kk++){
      const int col8 = kk*4 + quad;
      bf16x8 af[4], bfr[4];
      #pragma unroll
      for (int mi = 0; mi < 4; mi++){
        int row = wm*64 + mi*16 + l16;
        af[mi] = *(const bf16x8*)(As + row*64 + ((col8 ^ (row & 7)) * 8));
      }
      #pragma unroll
      for (int ni = 0; ni < 4; ni++){
        int row = wn*64 + ni*16 + l16;
        bfr[ni] = *(const bf16x8*)(Bs + row*64 + ((col8 ^ (row & 7)) * 8));
      }
      #pragma unroll
      for (int mi = 0; mi < 4; mi++)
        #pragma unroll
        for (int ni = 0; ni < 4; ni++)
          acc[mi][ni] = __builtin_amdgcn_mfma_f32_16x16x32_bf16(af[mi], bfr[ni], acc[mi][ni], 0, 0, 0);
    }
    __syncthreads();
  }
  // register epilogue: bias (+stats, +relu), round to bf16 into LDS [row][col]
  #pragma unroll
  for (int ni = 0; ni < 4; ni++){
    int colL = wn*64 + ni*16 + l16;
    float bb = bias[bn + colL];
    float s = 0.f, s2 = 0.f;
    #pragma unroll
    for (int mi = 0; mi < 4; mi++){
      int rbase = wm*64 + mi*16 + quad*4;
      #pragma unroll
      for (int r2 = 0; r2 < 4; r2++){
        int rowL = rbase + r2;
        float v = acc[mi][ni][r2] + bb;
        if (STATS && (bm + rowL) < M){ s += v; s2 += v * v; }
        if (MODE == 1) v = fmaxf(v, 0.f);
        S[rowL*128 + colL] = f2b(v);
      }
    }
    if (STATS){
      s  += __shfl_xor(s, 16, 64);  s  += __shfl_xor(s, 32, 64);
      s2 += __shfl_xor(s2, 16, 64); s2 += __shfl_xor(s2, 32, 64);
      if (quad == 0){
        int mb = bm >> 7;
        size_t bi = ((size_t)(mb*2 + wm)*2)*Nc + bn + colL;
        pst[bi] = s;
        pst[bi + Nc] = s2;
      }
    }
  }
  __syncthreads();
  // blast: 16B per lane, full-line coalesced stores
  #pragma unroll
  for (int it = 0; it < 8; it++){
    int idx = it*256 + tid;
    int rl = idx >> 4, cq = idx & 15;
    int row = bm + rl;
    if (row < M){
      int col0 = bn + cq*8;
      uint4 wv = *(const uint4*)(S + rl*128 + cq*8);
      uint4 ou;
      if (MODE == 3){
        float di = SCALE ? dv[row] : 1.f;
        float o[8], ov[8];
        up8(wv, o);
        uint4 old = *(const uint4*)(C + (size_t)row * Nc + col0);
        up8(old, ov);
        #pragma unroll
        for (int k = 0; k < 8; k++){
          int ch = col0 + k;
          float sc = scsh[ch];
          float sh = scsh[Nc + ch];
          o[k] += fmaxf(fmaf(ov[k], sc, sh), 0.f);
          if (SCALE) o[k] *= di;
        }
        ou.x = pk2(o[0], o[1]); ou.y = pk2(o[2], o[3]);
        ou.z = pk2(o[4], o[5]); ou.w = pk2(o[6], o[7]);
      } else if (SCALE){
        float di = dv[row];
        float o[8];
        up8(wv, o);
        #pragma unroll
        for (int k = 0; k < 8; k++) o[k] *= di;
        ou.x = pk2(o[0], o[1]); ou.y = pk2(o[2], o[3]);
        ou.z = pk2(o[4], o[5]); ou.w = pk2(o[6], o[7]);
      } else {
        ou = wv;
      }
      if (BLK){
        int chpg = Nc >> 3;                 // channels per XCD group
        int g = col0 / chpg;
        int c8g = chpg >> 3;                // uint4 per row slice
        int cl = (col0 - g * chpg) >> 3;
        *((uint4*)Co + (size_t)g*NN*c8g + (size_t)row*c8g + cl) = ou;
      } else {
        *(uint4*)(Co + (size_t)row * Nc + col0) = ou;
      }
    }
  }
}

// ---------------- fp32 split-K GEMM (MLP tail, M=256) ----------------
// Each block writes its K-chunk partial to Cp[z][M][Nc] with plain stores;
// k_redsk sums the SPLITS partials + bias.
template<bool RELUA>
__global__ __launch_bounds__(256) void k_gemm_sk(const float* __restrict__ A,
                                                 const float* __restrict__ B,
                                                 float* __restrict__ Cp,
                                                 int M, int K, int Nc){
  __shared__ float As[16][68];
  __shared__ float Bs[16][64];
  const int tid = threadIdx.x;
  const int tx = tid & 15, ty = tid >> 4;
  const int bm = blockIdx.x * 64, bn = blockIdx.y * 64;
  const int kchunk = K / gridDim.z;
  const int ks = blockIdx.z * kchunk, ke = ks + kchunk;
  const int arow = tid >> 2, akq = (tid & 3) << 2;
  const int brow = tid >> 4, bcol = (tid & 15) << 2;
  float acc[4][4] = {{0.f}};
  const bool aval = (bm + arow) < M;
  const float* Aptr = A + (size_t)(bm + arow) * K + akq;
  const float* Bptr = B + (size_t)brow * Nc + bn + bcol;
  for (int k0 = ks; k0 < ke; k0 += 16){
    float4 av = make_float4(0.f, 0.f, 0.f, 0.f);
    if (aval) av = *(const float4*)(Aptr + k0);
    if (RELUA){
      av.x = fmaxf(av.x, 0.f); av.y = fmaxf(av.y, 0.f);
      av.z = fmaxf(av.z, 0.f); av.w = fmaxf(av.w, 0.f);
    }
    float4 bv = *(const float4*)(Bptr + (size_t)k0 * Nc);
    As[akq + 0][arow] = av.x;
    As[akq + 1][arow] = av.y;
    As[akq + 2][arow] = av.z;
    As[akq + 3][arow] = av.w;
    *(float4*)&Bs[brow][bcol] = bv;
    __syncthreads();
    #pragma unroll
    for (int kk = 0; kk < 16; kk++){
      const float4 a = *(const float4*)(&As[kk][ty << 2]);
      const float4 b = *(const float4*)(&Bs[kk][tx << 2]);
      const float ar[4] = {a.x, a.y, a.z, a.w};
      const float br[4] = {b.x, b.y, b.z, b.w};
      #pragma unroll
      for (int i = 0; i < 4; i++)
        #pragma unroll
        for (int j = 0; j < 4; j++)
          acc[i][j] = fmaf(ar[i], br[j], acc[i][j]);
    }
    __syncthreads();
  }
  const int col = bn + (tx << 2);
  float* base = Cp + (size_t)blockIdx.z * M * Nc;
  #pragma unroll
  for (int i = 0; i < 4; i++){
    int row = bm + (ty << 2) + i;
    if (row < M){
      *(float4*)(base + (size_t)row * Nc + col) =
          make_float4(acc[i][0], acc[i][1], acc[i][2], acc[i][3]);
    }
  }
}

// reduce SPLITS partials + bias -> out (fp32, float4-vectorized)
template<int SPLITS>
__global__ __launch_bounds__(256) void k_redsk(const float4* __restrict__ part,
                                               const float* __restrict__ bias,
                                               float4* __restrict__ out,
                                               int M, int Nc4){
  int t = blockIdx.x*blockDim.x + threadIdx.x;
  int total = M * Nc4;
  if (t >= total) return;
  int col4 = t % Nc4;
  float4 s = ((const float4*)bias)[col4];
  #pragma unroll
  for (int z = 0; z < SPLITS; z++){
    float4 v = part[(size_t)z * total + t];
    s.x += v.x; s.y += v.y; s.z += v.z; s.w += v.w;
  }
  out[t] = s;
}

// ---------------- mean pool: h2 bf16 [NN,1024] -> pooled fp32 [NG,1024] ----------------
__global__ __launch_bounds__(256) void k_pool_b(const u16* __restrict__ h,
                                                const int* __restrict__ start,
                                                float* __restrict__ pooled){
  __shared__ float sm[128*8];
  int g = blockIdx.x;
  int half = threadIdx.x >> 7;
  int cb = threadIdx.x & 127;
  int c = cb << 3;
  int r0 = start[g], r1 = start[g + 1];
  float acc[8] = {0.f,0.f,0.f,0.f,0.f,0.f,0.f,0.f};
  for (int r = r0 + half; r < r1; r += 2){
    float b[8];
    up8(*(const uint4*)(h + (size_t)r * 1024 + c), b);
    #pragma unroll
    for (int k = 0; k < 8; k++) acc[k] += b[k];
  }
  if (half){
    #pragma unroll
    for (int k = 0; k < 8; k++) sm[cb*8 + k] = acc[k];
  }
  __syncthreads();
  if (!half){
    float inv = (r1 > r0) ? (1.0f / (float)(r1 - r0)) : 0.0f;
    float o[8];
    #pragma unroll
    for (int k = 0; k < 8; k++) o[k] = (acc[k] + sm[cb*8 + k]) * inv;
    float4* dst = (float4*)(pooled + (size_t)g * 1024 + c);
    dst[0] = make_float4(o[0], o[1], o[2], o[3]);
    dst[1] = make_float4(o[4], o[5], o[6], o[7]);
  }
}

// ---------------- host launcher ----------------

extern "C" void kernel_launch(void* const* d_in, const int* in_sizes, int n_in,
                              void* d_out, int out_size, void* d_ws, size_t ws_size,
                              hipStream_t stream) {
  const float* x    = (const float*)d_in[0];
  const int*   ei   = (const int*)d_in[1];
  const int*   bat  = (const int*)d_in[2];
  const float* w0   = (const float*)d_in[3];
  const float* b0   = (const float*)d_in[4];
  const float* a_w1 = (const float*)d_in[5],  *a_b1  = (const float*)d_in[6];
  const float* a_g1 = (const float*)d_in[7],  *a_be1 = (const float*)d_in[8];
  const float* a_w2 = (const float*)d_in[9],  *a_b2  = (const float*)d_in[10];
  const float* a_g2 = (const float*)d_in[11], *a_be2 = (const float*)d_in[12];
  const float* a_w3 = (const float*)d_in[13], *a_b3  = (const float*)d_in[14];
  const float* c_w1 = (const float*)d_in[15], *c_b1  = (const float*)d_in[16];
  const float* c_g1 = (const float*)d_in[17], *c_be1 = (const float*)d_in[18];
  const float* c_w2 = (const float*)d_in[19], *c_b2  = (const float*)d_in[20];
  const float* c_g2 = (const float*)d_in[21], *c_be2 = (const float*)d_in[22];
  const float* c_w3 = (const float*)d_in[23], *c_b3  = (const float*)d_in[24];
  const float* mw1  = (const float*)d_in[25], *mb1   = (const float*)d_in[26];
  const float* mw2  = (const float*)d_in[27], *mb2   = (const float*)d_in[28];
  float* out = (float*)d_out;

  char* pp = (char*)d_ws;
  auto alloc = [&](size_t b)->char*{ char* r = pp; pp += (b + 255) & ~(size_t)255; return r; };

  const size_t CH = (size_t)NN * 2;
  char* R = alloc(2304 * CH);                      // 92.16 MB
  float* dinv = (float*)alloc((size_t)NN * 4);
  int* icomb  = (int*)alloc((size_t)2 * NN * 4);   // deg + cur
  int* deg    = icomb;
  int* cur    = icomb + NN;
  int* offs   = (int*)alloc((size_t)(NN + 1) * 4);
  int* bsum   = (int*)alloc((size_t)(NB + 1) * 4);
  int* srcs   = (int*)alloc((size_t)NE * 4);
  int* startg = (int*)alloc((size_t)(NG + 1) * 4);
  float* SB   = (float*)alloc(5376 * 4);           // sc||sh per BN layer
  float* sA1 = SB;          // 2*384
  float* sA2 = SB + 768;    // 2*512
  float* sC1 = SB + 1792;   // 2*768
  float* sC2 = SB + 3328;   // 2*1024
  float* pstat = (float*)alloc((size_t)MBK * 2 * 2 * 1024 * 4);  // 2.57 MB stats scratch
  u16* WT  = (u16*)alloc(2162688 * 2);             // 4.33 MB
  u16* wt0  = WT;                // 256x128
  u16* wtA1 = WT + 32768;        // 384x256
  u16* wtA2 = WT + 131072;       // 512x384
  u16* wtA3 = WT + 327680;       // 512x256
  u16* wtC1 = WT + 458752;       // 768x512
  u16* wtC2 = WT + 851968;       // 1024x768
  u16* wtC3 = WT + 1638400;      // 1024x512
  float* P  = (float*)WT;        // overlaid with WT (disjoint lifetime)
  float* Hh = P + (size_t)NG * 1024;

  // slot map (lifetime-checked; blocked buffers marked [B]):
  //  xb[B]   0-127    k_cast -> agg(ax)
  //  ax      128-255  -> stem GEMM
  //  h0[B]   256-511  stem GEMM -> agg(ah0)
  //  ah0     512-767  -> GEMM wtA1, wtA3
  //  t1raw   768-1151 GEMM wtA1 -> bnscale
  //  t1b[B]  1152-1535 bnscale -> agg(at)
  //  at      1536-1919 -> GEMM wtA2
  //  h1raw   0-511    GEMM wtA2 -> mode3 old-read
  //  h1b[B]  768-1279 mode3 GEMM -> agg(ah1)
  //  ah1     1792-2303 -> GEMM wtC1, wtC3
  //  u1raw   0-767    GEMM wtC1 -> bnscale
  //  u1b[B]  768-1535 bnscale -> agg(au)
  //  au      0-767    -> GEMM wtC2
  //  h2      768-1791 GEMM wtC2 -> wtC3 (in-place RMW) -> pool
  //  part1   0-255    gemm_sk1 partials -> redsk1   [dead: au]
  //  part2   256-511  gemm_sk2 partials -> redsk2
  auto slot = [&](int s)->u16*{ return (u16*)(R + (size_t)s * CH); };
  u16* xb    = slot(0);
  u16* ax    = slot(128);
  u16* h0    = slot(256);
  u16* ah0   = slot(512);
  u16* t1raw = slot(768);
  u16* t1b   = slot(1152);
  u16* at    = slot(1536);
  u16* h1raw = slot(0);
  u16* h1b   = slot(768);
  u16* ah1   = slot(1792);
  u16* u1raw = slot(0);
  u16* u1b   = slot(768);
  u16* au    = slot(0);
  u16* h2    = slot(768);
  float* part1 = (float*)slot(0);
  float* part2 = (float*)slot(256);

  auto cdiv = [](int a, int b){ return (a + b - 1) / b; };

  // graph preprocessing
  k_zero<<<cdiv(2*NN,256),256,0,stream>>>(icomb, 2*NN);
  k_deg <<<cdiv(NE,256),256,0,stream>>>(ei, deg);
  k_scan1<<<NB,256,0,stream>>>(deg, bsum, dinv);
  k_scan2<<<1,64,0,stream>>>(bsum);
  k_scan3<<<NB,256,0,stream>>>(deg, bsum, offs);
  k_fill<<<cdiv(NE,256),256,0,stream>>>(ei, offs, cur, srcs);
  k_bounds<<<cdiv(NN,256),256,0,stream>>>(bat, startg);
  k_cast<<<cdiv(NN*16,256),256,0,stream>>>(x, (uint4*)xb, dinv, NN*16);

  // merged weight prep (fp32 [K,N] -> bf16 [N,K], 7 weights, 1 launch)
  {
    WPArgs wa;
    const float* ws[7] = {w0, a_w1, a_w2, a_w3, c_w1, c_w2, c_w3};
    u16* wts[7] = {wt0, wtA1, wtA2, wtA3, wtC1, wtC2, wtC3};
    int Ks[7] = {128, 256, 384, 256, 512, 768, 512};
    int Ns[7] = {256, 384, 512, 512, 768, 1024, 1024};
    int acc = 0;
    for (int i = 0; i < 7; i++){
      wa.w[i] = ws[i]; wa.wt[i] = wts[i]; wa.K[i] = Ks[i]; wa.N[i] = Ns[i];
      wa.tstart[i] = acc;
      acc += (Ks[i]/64) * (Ns[i]/64);
    }
    wa.tstart[7] = acc;
    k_wprep7<<<acc,256,0,stream>>>(wa);
  }

  // agg: blocked-gather, 8 XCD groups always
  auto agg = [&](const u16* in, u16* o, int C){
    int C8 = C / 8;
    int C8G = C8 / 8;
    int gb = 8 * cdiv(NN * C8G, 256);
    switch (C8){
      case 16: k_agg_b<16, 2><<<gb,256,0,stream>>>((const uint4*)in,(uint4*)o,dinv,offs,srcs); break;
      case 32: k_agg_b<32, 4><<<gb,256,0,stream>>>((const uint4*)in,(uint4*)o,dinv,offs,srcs); break;
      case 48: k_agg_b<48, 6><<<gb,256,0,stream>>>((const uint4*)in,(uint4*)o,dinv,offs,srcs); break;
      case 64: k_agg_b<64, 8><<<gb,256,0,stream>>>((const uint4*)in,(uint4*)o,dinv,offs,srcs); break;
      case 96: k_agg_b<96,12><<<gb,256,0,stream>>>((const uint4*)in,(uint4*)o,dinv,offs,srcs); break;
      default: break;
    }
  };
  // GEMM modes: 0 = raw+stats-partials (row-major); 1b = relu*dinv, BLOCKED out;
  // 3b = (relu(sc*old+sh)+acc)*dinv, BLOCKED out; 3 = relu(sc*old+sh)+acc, row-major in-place
  auto gemm0 = [&](const u16* A, const u16* BT_, const float* bi, u16* Cc,
                   int K, int Nc){
    dim3 g(Nc/128, cdiv(NN,128));
    k_mfma<0,true,false,false><<<g,256,0,stream>>>(A, BT_, bi, Cc, Cc, pstat, nullptr, dinv, NN, K, Nc);
  };
  auto bncoef = [&](const float* gm, const float* bt, float* scsh, int Nc){
    k_bncoef<<<Nc/32,256,0,stream>>>(pstat, gm, bt, scsh, Nc);
  };
  auto gemm1b = [&](const u16* A, const u16* BT_, const float* bi, u16* Cob,
                    int K, int Nc){
    dim3 g(Nc/128, cdiv(NN,128));
    k_mfma<1,false,true,true><<<g,256,0,stream>>>(A, BT_, bi, Cob, Cob, nullptr, nullptr, dinv, NN, K, Nc);
  };
  auto gemm3b = [&](const u16* A, const u16* BT_, const float* bi, const u16* Cold, u16* Cob,
                    int K, int Nc, const float* scsh){
    dim3 g(Nc/128, cdiv(NN,128));
    k_mfma<3,false,true,true><<<g,256,0,stream>>>(A, BT_, bi, Cold, Cob, nullptr, scsh, dinv, NN, K, Nc);
  };
  auto gemm3 = [&](const u16* A, const u16* BT_, const float* bi, u16* Cc,
                   int K, int Nc, const float* scsh){
    dim3 g(Nc/128, cdiv(NN,128));
    k_mfma<3,false,false,false><<<g,256,0,stream>>>(A, BT_, bi, Cc, Cc, nullptr, scsh, dinv, NN, K, Nc);
  };

  // stem
  agg(xb, ax, 128);
  gemm1b(ax, wt0, b0, h0, 128, 256);                       // h0[B] = relu(ax@w0+b0)*dinv
  // block0 (256 -> 384 -> 512)
  agg(h0, ah0, 256);
  gemm0(ah0, wtA1, a_b1, t1raw, 256, 384);                 // t1raw + stats partials
  bncoef(a_g1, a_be1, sA1, 384);
  k_bnscale<48><<<cdiv(NN*48,256),256,0,stream>>>((const uint4*)t1raw, (uint4*)t1b, dinv, sA1);
  agg(t1b, at, 384);                                       // at = agg(T(t1raw))
  gemm0(at, wtA2, a_b2, h1raw, 384, 512);                  // t2raw + stats partials
  bncoef(a_g2, a_be2, sA2, 512);
  gemm3b(ah0, wtA3, a_b3, h1raw, h1b, 256, 512, sA2);      // h1b[B]
  // block1 (512 -> 768 -> 1024)
  agg(h1b, ah1, 512);
  gemm0(ah1, wtC1, c_b1, u1raw, 512, 768);                 // u1raw + stats partials
  bncoef(c_g1, c_be1, sC1, 768);
  k_bnscale<96><<<cdiv(NN*96,256),256,0,stream>>>((const uint4*)u1raw, (uint4*)u1b, dinv, sC1);
  agg(u1b, au, 768);                                       // au = agg(T(u1raw))
  gemm0(au, wtC2, c_b2, h2, 768, 1024);                    // u2raw + stats partials
  bncoef(c_g2, c_be2, sC2, 1024);
  gemm3(ah1, wtC3, c_b3, h2, 512, 1024, sC2);              // h2 final (row-major)
  // pool + MLP (fp32 split-K, partials + reduce — no global atomics)
  k_pool_b<<<NG,256,0,stream>>>(h2, startg, P);
  {
    dim3 g1(cdiv(NG,64), 1024/64, 8);
    k_gemm_sk<false><<<g1,256,0,stream>>>(P, mw1, part1, NG, 1024, 1024);
    k_redsk<8><<<cdiv(NG*256,256),256,0,stream>>>((const float4*)part1, mb1, (float4*)Hh, NG, 256);
    dim3 g2(cdiv(NG,64), 768/64, 8);
    k_gemm_sk<true><<<g2,256,0,stream>>>(Hh, mw2, part2, NG, 1024, 768);
    k_redsk<8><<<cdiv(NG*192,256),256,0,stream>>>((const float4*)part2, mb2, (float4*)out, NG, 192);
  }
}